// Round 3
// baseline (520.708 us; speedup 1.0000x reference)
//
#include <hip/hip_runtime.h>
#include <hip/hip_bf16.h>
#include <stdint.h>

typedef __attribute__((ext_vector_type(8))) short short8;
typedef __attribute__((ext_vector_type(4))) float f32x4;

__device__ __forceinline__ float bf2f(short u) {
  return __uint_as_float(((unsigned)(unsigned short)u) << 16);
}
__device__ __forceinline__ short f2bf(float f) {
  unsigned x = __float_as_uint(f);
  unsigned r = (x + 0x7fffu + ((x >> 16) & 1u)) >> 16;
  return (short)r;
}

__device__ __forceinline__ void gload_lds16(const short* g, short* l) {
  __builtin_amdgcn_global_load_lds(
      (const __attribute__((address_space(1))) void*)g,
      (__attribute__((address_space(3))) void*)l, 16, 0, 0);
}

// ---------------- cast x (f32 -> bf16), 8 elems/thread ----------------
__global__ void cast_x_bf16(const float* __restrict__ in, short* __restrict__ out, int n8) {
  int i = blockIdx.x * blockDim.x + threadIdx.x;
  if (i >= n8) return;
  const float4* p = (const float4*)in + (size_t)i * 2;
  float4 a = p[0], b = p[1];
  short8 o;
  o[0] = f2bf(a.x); o[1] = f2bf(a.y); o[2] = f2bf(a.z); o[3] = f2bf(a.w);
  o[4] = f2bf(b.x); o[5] = f2bf(b.y); o[6] = f2bf(b.z); o[7] = f2bf(b.w);
  *((short8*)out + i) = o;
}

// ------------- transpose + cast: out[row_off + c][r] = in[r][c] -------------
__global__ void transpose_cast(const float* __restrict__ in, int R, int C,
                               short* __restrict__ out, int row_off, int ldo) {
  __shared__ float tile[32][33];
  int c0 = blockIdx.x * 32, r0 = blockIdx.y * 32;
  int tx = threadIdx.x, ty = threadIdx.y;
#pragma unroll
  for (int i = 0; i < 4; ++i)
    tile[ty + i * 8][tx] = in[(size_t)(r0 + ty + i * 8) * C + (c0 + tx)];
  __syncthreads();
#pragma unroll
  for (int i = 0; i < 4; ++i)
    out[(size_t)(row_off + c0 + ty + i * 8) * ldo + (r0 + tx)] =
        f2bf(tile[tx][ty + i * 8]);
}

// ---------------- GEMM: C = A[M,K] * Bt[N,K]^T ----------------
template <int OUT_F32>
__global__ __launch_bounds__(256)
void gemm_bt(const short* __restrict__ A, const short* __restrict__ Bt,
             int M, int N, int K, int ldc,
             short* __restrict__ outb, float* __restrict__ outf,
             const float* __restrict__ bias) {
  __shared__ short As[128 * 64];
  __shared__ short Bs[128 * 64];
  const int tid = threadIdx.x, lane = tid & 63;
  const int wr = tid >> 7, wc = (tid >> 6) & 1;
  const int l15 = lane & 15, l4 = lane >> 4;
  const int m0 = blockIdx.y * 128, n0 = blockIdx.x * 128;
  f32x4 acc[4][4] = {};
  for (int k0 = 0; k0 < K; k0 += 64) {
#pragma unroll
    for (int iss = 0; iss < 4; ++iss) {
      int c = iss * 256 + tid;
      int row = c >> 3, q = c & 7;
      gload_lds16(A + (size_t)(m0 + row) * K + k0 + q * 8,
                  As + iss * 2048 + (tid & 192) * 8);
      gload_lds16(Bt + (size_t)(n0 + row) * K + k0 + q * 8,
                  Bs + iss * 2048 + (tid & 192) * 8);
    }
    __syncthreads();
#pragma unroll
    for (int kk = 0; kk < 2; ++kk) {
      short8 a[4], b[4];
#pragma unroll
      for (int mi = 0; mi < 4; ++mi)
        a[mi] = *(const short8*)(As + (wr * 64 + mi * 16 + l15) * 64 + kk * 32 + l4 * 8);
#pragma unroll
      for (int ni = 0; ni < 4; ++ni)
        b[ni] = *(const short8*)(Bs + (wc * 64 + ni * 16 + l15) * 64 + kk * 32 + l4 * 8);
#pragma unroll
      for (int mi = 0; mi < 4; ++mi)
#pragma unroll
        for (int ni = 0; ni < 4; ++ni)
          acc[mi][ni] = __builtin_amdgcn_mfma_f32_16x16x32_bf16(a[mi], b[ni], acc[mi][ni], 0, 0, 0);
    }
    __syncthreads();
  }
#pragma unroll
  for (int mi = 0; mi < 4; ++mi)
#pragma unroll
    for (int ni = 0; ni < 4; ++ni)
#pragma unroll
      for (int r = 0; r < 4; ++r) {
        int row = m0 + wr * 64 + mi * 16 + l4 * 4 + r;
        int col = n0 + wc * 64 + ni * 16 + l15;
        if (OUT_F32)
          outf[(size_t)row * ldc + col] = acc[mi][ni][r] + bias[col];
        else
          outb[(size_t)row * ldc + col] = f2bf(acc[mi][ni][r]);
      }
}

// ---------------- RoPE in-place on qkv ----------------
__global__ void rope_kernel(short* __restrict__ qkv, const int* __restrict__ segpos,
                            int nheads, int hd, int ld) {
  const int row = blockIdx.x;
  const float pos = (float)segpos[row];
  short* base = qkv + (size_t)row * ld;
  const int quarter = hd >> 2;
  const int npairs_q = nheads * quarter;
  const int total = npairs_q + quarter;
  for (int p = threadIdx.x; p < total; p += blockDim.x) {
    int i, off;
    if (p < npairs_q) { off = (p >> 5) * hd; i = p & 31; }
    else              { off = nheads * hd;  i = p - npairs_q; }
    float ang = pos * exp2f(-(float)i * (13.287712379549449f / (float)quarter));
    float s, c;
    sincosf(ang, &s, &c);
    float a = bf2f(base[off + i]);
    float b = bf2f(base[off + quarter + i]);
    base[off + i]           = f2bf(a * c - b * s);
    base[off + quarter + i] = f2bf(b * c + a * s);
  }
}

// ---------------- windowed causal flash attention (MQA), H=128 ----------------
// 512 threads = 8 waves x 16 q-rows = 128 q-rows per block. 1D grid, LPT order.
#define SWZV(h) ((((h) ^ ((h) >> 3)) & 7) << 4)
__global__ __launch_bounds__(512, 4)
void attn_kernel(const short* __restrict__ qkv, short* __restrict__ enc,
                 const int* __restrict__ wsz_p, int T, int nheads, int nqt, int bhc) {
  const int window = wsz_p[0];
  const int i = blockIdx.x;
  const int qt = nqt - 1 - (i / bhc);   // heavy tiles dispatched first (LPT)
  const int bh = i % bhc;
  const int b = bh / nheads, n = bh % nheads;
  const int tid = threadIdx.x, lane = tid & 63, w = tid >> 6;
  const int l15 = lane & 15, l4 = lane >> 4;
  const int q0 = qt * 128;
  const size_t rowbase = (size_t)b * T;
  const int LD = nheads * 128 + 256;    // 2304
  const int kcol = nheads * 128;
  const float CC = 0.08838834764831845f * 1.4426950408889634f;

  __shared__ short Ks[64 * 128];        // [s][h], rows swizzled by (s&7)<<4
  __shared__ short Vt[128 * 64];        // [h][s], rows swizzled by SWZV(h)
  __shared__ short Pl[8][16 * 72];

  short8 qf[4];
  {
    const short* qptr = qkv + (rowbase + q0 + w * 16 + l15) * LD + n * 128 + l4 * 8;
#pragma unroll
    for (int kk = 0; kk < 4; ++kk) qf[kk] = *(const short8*)(qptr + kk * 32);
  }
  f32x4 o[8] = {};
  float mrow[4], lrow[4];
#pragma unroll
  for (int r = 0; r < 4; ++r) { mrow[r] = -1e30f; lrow[r] = 0.f; }

  const int tmin = q0 + w * 16, tmax = tmin + 15;
  int st_lo = q0 - window; if (st_lo < 0) st_lo = 0; st_lo >>= 6;
  const int st_hi = (q0 + 127) >> 6;

  short8 kreg[2], vreg[2];
  auto load_tile = [&](int s0) {
#pragma unroll
    for (int it = 0; it < 2; ++it) {
      int c = it * 512 + tid;
      int r = c >> 4, cg = c & 15;
      const short* rowp = qkv + (rowbase + s0 + r) * (size_t)LD + kcol;
      kreg[it] = *(const short8*)(rowp + cg * 8);
      vreg[it] = *(const short8*)(rowp + 128 + cg * 8);
    }
  };
  auto store_tile = [&]() {
#pragma unroll
    for (int it = 0; it < 2; ++it) {
      int c = it * 512 + tid;
      int r = c >> 4, cg = c & 15;
      *(short8*)((char*)Ks + ((r * 256 + cg * 16) ^ ((r & 7) << 4))) = kreg[it];
      int h0 = cg * 8;
#pragma unroll
      for (int j = 0; j < 8; ++j) {
        int h = h0 + j;
        *(short*)((char*)Vt + ((h * 128 + r * 2) ^ SWZV(h))) = vreg[it][j];
      }
    }
  };

  load_tile(st_lo * 64);
  store_tile();
  __syncthreads();

  for (int st = st_lo; st <= st_hi; ++st) {
    const int s0 = st * 64;
    const bool more = (st < st_hi);
    if (more) load_tile(s0 + 64);

    const bool active = (s0 <= tmax) && (tmin <= s0 + 63 + window);
    if (active) {
      f32x4 sacc[4];
      __builtin_amdgcn_s_setprio(1);
#pragma unroll
      for (int si = 0; si < 4; ++si) {
        f32x4 acc = {};
        int srow = si * 16 + l15;
#pragma unroll
        for (int kk = 0; kk < 4; ++kk) {
          int byt = (srow * 256 + (kk * 32 + l4 * 8) * 2) ^ ((srow & 7) << 4);
          short8 kf = *(const short8*)((const char*)Ks + byt);
          acc = __builtin_amdgcn_mfma_f32_16x16x32_bf16(qf[kk], kf, acc, 0, 0, 0);
        }
        sacc[si] = acc;
      }
      __builtin_amdgcn_s_setprio(0);

      const int trow0 = q0 + w * 16 + l4 * 4;
      float mt[4];
#pragma unroll
      for (int r = 0; r < 4; ++r) mt[r] = -1e30f;
#pragma unroll
      for (int si = 0; si < 4; ++si) {
        int s = s0 + si * 16 + l15;
#pragma unroll
        for (int r = 0; r < 4; ++r) {
          int t = trow0 + r;
          float v = (s <= t && t <= s + window) ? sacc[si][r] : -1e30f;
          sacc[si][r] = v;
          mt[r] = fmaxf(mt[r], v);
        }
      }
#pragma unroll
      for (int r = 0; r < 4; ++r)
#pragma unroll
        for (int off = 1; off < 16; off <<= 1)
          mt[r] = fmaxf(mt[r], __shfl_xor(mt[r], off));

      bool dfr = true;
#pragma unroll
      for (int r = 0; r < 4; ++r) dfr = dfr && ((mt[r] - mrow[r]) * CC <= 8.0f);
      const bool defer = __all(dfr);
      float fac[4];
      if (!defer) {
#pragma unroll
        for (int r = 0; r < 4; ++r) {
          float mnew = fmaxf(mrow[r], mt[r]);
          fac[r] = exp2f((mrow[r] - mnew) * CC);
          mrow[r] = mnew;
        }
      }
      float psum[4];
#pragma unroll
      for (int r = 0; r < 4; ++r) psum[r] = 0.f;
#pragma unroll
      for (int si = 0; si < 4; ++si)
#pragma unroll
        for (int r = 0; r < 4; ++r) {
          float p = exp2f((sacc[si][r] - mrow[r]) * CC);
          psum[r] += p;
          Pl[w][(l4 * 4 + r) * 72 + si * 16 + l15] = f2bf(p);
        }
#pragma unroll
      for (int r = 0; r < 4; ++r) {
#pragma unroll
        for (int off = 1; off < 16; off <<= 1)
          psum[r] += __shfl_xor(psum[r], off);
        if (!defer) lrow[r] = lrow[r] * fac[r] + psum[r];
        else        lrow[r] += psum[r];
      }
      if (!defer) {
#pragma unroll
        for (int nt = 0; nt < 8; ++nt)
#pragma unroll
          for (int r = 0; r < 4; ++r) o[nt][r] *= fac[r];
      }

      __builtin_amdgcn_s_setprio(1);
#pragma unroll
      for (int kk = 0; kk < 2; ++kk) {
        short8 pf = *(const short8*)(&Pl[w][l15 * 72 + kk * 32 + l4 * 8]);
#pragma unroll
        for (int nt = 0; nt < 8; ++nt) {
          int h = nt * 16 + l15;
          int vb = (h * 128 + kk * 64 + l4 * 16) ^ SWZV(h);
          short8 vf = *(const short8*)((const char*)Vt + vb);
          o[nt] = __builtin_amdgcn_mfma_f32_16x16x32_bf16(pf, vf, o[nt], 0, 0, 0);
        }
      }
      __builtin_amdgcn_s_setprio(0);
    }
    __syncthreads();
    if (more) store_tile();
    __syncthreads();
  }

#pragma unroll
  for (int nt = 0; nt < 8; ++nt)
#pragma unroll
    for (int r = 0; r < 4; ++r) {
      size_t row = rowbase + q0 + w * 16 + l4 * 4 + r;
      int col = n * 128 + nt * 16 + l15;
      enc[row * (size_t)(nheads * 128) + col] = f2bf(o[nt][r] / lrow[r]);
    }
}

extern "C" void kernel_launch(void* const* d_in, const int* in_sizes, int n_in,
                              void* d_out, int out_size, void* d_ws, size_t ws_size,
                              hipStream_t stream) {
  const float* x     = (const float*)d_in[0];
  const float* w_q   = (const float*)d_in[1];
  const float* w_k   = (const float*)d_in[2];
  const float* w_v   = (const float*)d_in[3];
  const float* w_out = (const float*)d_in[4];
  const float* b_out = (const float*)d_in[5];
  const int* segpos  = (const int*)d_in[6];
  const int* wsz     = (const int*)d_in[8];
  float* out = (float*)d_out;

  const int BT = in_sizes[6];          // 4096
  const int W  = in_sizes[5];          // 2048
  const int H  = in_sizes[2] / W;      // 128
  const int NH = W / H;                // 16
  const int T  = 2048;
  const int NQKV = W + 2 * H;          // 2304

  char* ws = (char*)d_ws;
  short* xb    = (short*)ws;
  short* wqkvT = (short*)(ws + (size_t)BT * W * 2);
  short* woutT = (short*)(ws + (size_t)(BT * W + NQKV * W) * 2);
  short* qkv   = (short*)(ws + (size_t)(BT * W + NQKV * W + W * W) * 2);
  short* enc   = xb;

  int n8 = BT * W / 8;
  cast_x_bf16<<<(n8 + 255) / 256, 256, 0, stream>>>(x, xb, n8);

  dim3 tb(32, 8);
  transpose_cast<<<dim3(W / 32, W / 32), tb, 0, stream>>>(w_q, W, W, wqkvT, 0, W);
  transpose_cast<<<dim3(H / 32, W / 32), tb, 0, stream>>>(w_k, W, H, wqkvT, W, W);
  transpose_cast<<<dim3(H / 32, W / 32), tb, 0, stream>>>(w_v, W, H, wqkvT, W + H, W);
  transpose_cast<<<dim3(W / 32, W / 32), tb, 0, stream>>>(w_out, W, W, woutT, 0, W);

  gemm_bt<0><<<dim3(NQKV / 128, BT / 128), 256, 0, stream>>>(
      xb, wqkvT, BT, NQKV, W, NQKV, qkv, nullptr, nullptr);

  rope_kernel<<<BT, 256, 0, stream>>>(qkv, segpos, NH, H, NQKV);

  const int nqt = T / 128;
  const int bhc = (BT / T) * NH;
  attn_kernel<<<nqt * bhc, 512, 0, stream>>>(qkv, enc, wsz, T, NH, nqt, bhc);

  gemm_bt<1><<<dim3(W / 128, BT / 128), 256, 0, stream>>>(
      enc, woutT, BT, W, W, W, nullptr, out, b_out);
}

// Round 4
// 378.694 us; speedup vs baseline: 1.3750x; 1.3750x over previous
//
#include <hip/hip_runtime.h>
#include <hip/hip_bf16.h>
#include <stdint.h>

typedef __attribute__((ext_vector_type(8))) short short8;
typedef __attribute__((ext_vector_type(4))) float f32x4;

__device__ __forceinline__ float bf2f(short u) {
  return __uint_as_float(((unsigned)(unsigned short)u) << 16);
}
__device__ __forceinline__ short f2bf(float f) {
  unsigned x = __float_as_uint(f);
  unsigned r = (x + 0x7fffu + ((x >> 16) & 1u)) >> 16;
  return (short)r;
}

__device__ __forceinline__ void gload_lds16(const short* g, short* l) {
  __builtin_amdgcn_global_load_lds(
      (const __attribute__((address_space(1))) void*)g,
      (__attribute__((address_space(3))) void*)l, 16, 0, 0);
}

// ---------------- cast x (f32 -> bf16), 8 elems/thread ----------------
__global__ void cast_x_bf16(const float* __restrict__ in, short* __restrict__ out, int n8) {
  int i = blockIdx.x * blockDim.x + threadIdx.x;
  if (i >= n8) return;
  const float4* p = (const float4*)in + (size_t)i * 2;
  float4 a = p[0], b = p[1];
  short8 o;
  o[0] = f2bf(a.x); o[1] = f2bf(a.y); o[2] = f2bf(a.z); o[3] = f2bf(a.w);
  o[4] = f2bf(b.x); o[5] = f2bf(b.y); o[6] = f2bf(b.z); o[7] = f2bf(b.w);
  *((short8*)out + i) = o;
}

// ------------- transpose + cast: out[row_off + c][r] = in[r][c] -------------
__global__ void transpose_cast(const float* __restrict__ in, int R, int C,
                               short* __restrict__ out, int row_off, int ldo) {
  __shared__ float tile[32][33];
  int c0 = blockIdx.x * 32, r0 = blockIdx.y * 32;
  int tx = threadIdx.x, ty = threadIdx.y;
#pragma unroll
  for (int i = 0; i < 4; ++i)
    tile[ty + i * 8][tx] = in[(size_t)(r0 + ty + i * 8) * C + (c0 + tx)];
  __syncthreads();
#pragma unroll
  for (int i = 0; i < 4; ++i)
    out[(size_t)(row_off + c0 + ty + i * 8) * ldo + (r0 + tx)] =
        f2bf(tile[tx][ty + i * 8]);
}

// ---------------- GEMM: C = A[M,K] * Bt[N,K]^T ----------------
template <int OUT_F32>
__global__ __launch_bounds__(256)
void gemm_bt(const short* __restrict__ A, const short* __restrict__ Bt,
             int M, int N, int K, int ldc,
             short* __restrict__ outb, float* __restrict__ outf,
             const float* __restrict__ bias) {
  __shared__ short As[128 * 64];
  __shared__ short Bs[128 * 64];
  const int tid = threadIdx.x, lane = tid & 63;
  const int wr = tid >> 7, wc = (tid >> 6) & 1;
  const int l15 = lane & 15, l4 = lane >> 4;
  const int m0 = blockIdx.y * 128, n0 = blockIdx.x * 128;
  f32x4 acc[4][4] = {};
  for (int k0 = 0; k0 < K; k0 += 64) {
#pragma unroll
    for (int iss = 0; iss < 4; ++iss) {
      int c = iss * 256 + tid;
      int row = c >> 3, q = c & 7;
      gload_lds16(A + (size_t)(m0 + row) * K + k0 + q * 8,
                  As + iss * 2048 + (tid & 192) * 8);
      gload_lds16(Bt + (size_t)(n0 + row) * K + k0 + q * 8,
                  Bs + iss * 2048 + (tid & 192) * 8);
    }
    __syncthreads();
#pragma unroll
    for (int kk = 0; kk < 2; ++kk) {
      short8 a[4], b[4];
#pragma unroll
      for (int mi = 0; mi < 4; ++mi)
        a[mi] = *(const short8*)(As + (wr * 64 + mi * 16 + l15) * 64 + kk * 32 + l4 * 8);
#pragma unroll
      for (int ni = 0; ni < 4; ++ni)
        b[ni] = *(const short8*)(Bs + (wc * 64 + ni * 16 + l15) * 64 + kk * 32 + l4 * 8);
#pragma unroll
      for (int mi = 0; mi < 4; ++mi)
#pragma unroll
        for (int ni = 0; ni < 4; ++ni)
          acc[mi][ni] = __builtin_amdgcn_mfma_f32_16x16x32_bf16(a[mi], b[ni], acc[mi][ni], 0, 0, 0);
    }
    __syncthreads();
  }
#pragma unroll
  for (int mi = 0; mi < 4; ++mi)
#pragma unroll
    for (int ni = 0; ni < 4; ++ni)
#pragma unroll
      for (int r = 0; r < 4; ++r) {
        int row = m0 + wr * 64 + mi * 16 + l4 * 4 + r;
        int col = n0 + wc * 64 + ni * 16 + l15;
        if (OUT_F32)
          outf[(size_t)row * ldc + col] = acc[mi][ni][r] + bias[col];
        else
          outb[(size_t)row * ldc + col] = f2bf(acc[mi][ni][r]);
      }
}

// ---------------- RoPE in-place on qkv ----------------
__global__ void rope_kernel(short* __restrict__ qkv, const int* __restrict__ segpos,
                            int nheads, int hd, int ld) {
  const int row = blockIdx.x;
  const float pos = (float)segpos[row];
  short* base = qkv + (size_t)row * ld;
  const int quarter = hd >> 2;
  const int npairs_q = nheads * quarter;
  const int total = npairs_q + quarter;
  for (int p = threadIdx.x; p < total; p += blockDim.x) {
    int i, off;
    if (p < npairs_q) { off = (p >> 5) * hd; i = p & 31; }
    else              { off = nheads * hd;  i = p - npairs_q; }
    float ang = pos * exp2f(-(float)i * (13.287712379549449f / (float)quarter));
    float s, c;
    sincosf(ang, &s, &c);
    float a = bf2f(base[off + i]);
    float b = bf2f(base[off + quarter + i]);
    base[off + i]           = f2bf(a * c - b * s);
    base[off + quarter + i] = f2bf(b * c + a * s);
  }
}

// ---------------- windowed causal flash attention (MQA), H=128 ----------------
// 512 threads = 8 waves x 16 q-rows = 128 q-rows per block. 1D grid, LPT order.
// NOTE: no min-waves clamp in launch_bounds — (512,4) forced VGPR=64 and
// spilled ~300MB/dispatch to scratch (R3 counters: FETCH 268MB, dur 257us).
#define SWZV(h) ((((h) ^ ((h) >> 3)) & 7) << 4)
__global__ __launch_bounds__(512)
void attn_kernel(const short* __restrict__ qkv, short* __restrict__ enc,
                 const int* __restrict__ wsz_p, int T, int nheads, int nqt, int bhc) {
  const int window = wsz_p[0];
  const int i = blockIdx.x;
  const int qt = nqt - 1 - (i / bhc);   // heavy tiles dispatched first (LPT)
  const int bh = i % bhc;
  const int b = bh / nheads, n = bh % nheads;
  const int tid = threadIdx.x, lane = tid & 63, w = tid >> 6;
  const int l15 = lane & 15, l4 = lane >> 4;
  const int q0 = qt * 128;
  const size_t rowbase = (size_t)b * T;
  const int LD = nheads * 128 + 256;    // 2304
  const int kcol = nheads * 128;
  const float CC = 0.08838834764831845f * 1.4426950408889634f;

  __shared__ short Ks[64 * 128];        // [s][h], rows swizzled by (s&7)<<4
  __shared__ short Vt[128 * 64];        // [h][s], rows swizzled by SWZV(h)
  __shared__ short Pl[8][16 * 72];

  short8 qf[4];
  {
    const short* qptr = qkv + (rowbase + q0 + w * 16 + l15) * LD + n * 128 + l4 * 8;
#pragma unroll
    for (int kk = 0; kk < 4; ++kk) qf[kk] = *(const short8*)(qptr + kk * 32);
  }
  f32x4 o[8] = {};
  float mrow[4], lrow[4];
#pragma unroll
  for (int r = 0; r < 4; ++r) { mrow[r] = -1e30f; lrow[r] = 0.f; }

  const int tmin = q0 + w * 16, tmax = tmin + 15;
  int st_lo = q0 - window; if (st_lo < 0) st_lo = 0; st_lo >>= 6;
  const int st_hi = (q0 + 127) >> 6;

  short8 kreg[2], vreg[2];
  auto load_tile = [&](int s0) {
#pragma unroll
    for (int it = 0; it < 2; ++it) {
      int c = it * 512 + tid;
      int r = c >> 4, cg = c & 15;
      const short* rowp = qkv + (rowbase + s0 + r) * (size_t)LD + kcol;
      kreg[it] = *(const short8*)(rowp + cg * 8);
      vreg[it] = *(const short8*)(rowp + 128 + cg * 8);
    }
  };
  auto store_tile = [&]() {
#pragma unroll
    for (int it = 0; it < 2; ++it) {
      int c = it * 512 + tid;
      int r = c >> 4, cg = c & 15;
      *(short8*)((char*)Ks + ((r * 256 + cg * 16) ^ ((r & 7) << 4))) = kreg[it];
      int h0 = cg * 8;
#pragma unroll
      for (int j = 0; j < 8; ++j) {
        int h = h0 + j;
        *(short*)((char*)Vt + ((h * 128 + r * 2) ^ SWZV(h))) = vreg[it][j];
      }
    }
  };

  load_tile(st_lo * 64);
  store_tile();
  __syncthreads();

  for (int st = st_lo; st <= st_hi; ++st) {
    const int s0 = st * 64;
    const bool more = (st < st_hi);
    if (more) load_tile(s0 + 64);

    const bool active = (s0 <= tmax) && (tmin <= s0 + 63 + window);
    if (active) {
      f32x4 sacc[4];
      __builtin_amdgcn_s_setprio(1);
#pragma unroll
      for (int si = 0; si < 4; ++si) {
        f32x4 acc = {};
        int srow = si * 16 + l15;
#pragma unroll
        for (int kk = 0; kk < 4; ++kk) {
          int byt = (srow * 256 + (kk * 32 + l4 * 8) * 2) ^ ((srow & 7) << 4);
          short8 kf = *(const short8*)((const char*)Ks + byt);
          acc = __builtin_amdgcn_mfma_f32_16x16x32_bf16(qf[kk], kf, acc, 0, 0, 0);
        }
        sacc[si] = acc;
      }
      __builtin_amdgcn_s_setprio(0);

      const int trow0 = q0 + w * 16 + l4 * 4;
      float mt[4];
#pragma unroll
      for (int r = 0; r < 4; ++r) mt[r] = -1e30f;
#pragma unroll
      for (int si = 0; si < 4; ++si) {
        int s = s0 + si * 16 + l15;
#pragma unroll
        for (int r = 0; r < 4; ++r) {
          int t = trow0 + r;
          float v = (s <= t && t <= s + window) ? sacc[si][r] : -1e30f;
          sacc[si][r] = v;
          mt[r] = fmaxf(mt[r], v);
        }
      }
#pragma unroll
      for (int r = 0; r < 4; ++r)
#pragma unroll
        for (int off = 1; off < 16; off <<= 1)
          mt[r] = fmaxf(mt[r], __shfl_xor(mt[r], off));

      bool dfr = true;
#pragma unroll
      for (int r = 0; r < 4; ++r) dfr = dfr && ((mt[r] - mrow[r]) * CC <= 8.0f);
      const bool defer = __all(dfr);
      float fac[4];
      if (!defer) {
#pragma unroll
        for (int r = 0; r < 4; ++r) {
          float mnew = fmaxf(mrow[r], mt[r]);
          fac[r] = exp2f((mrow[r] - mnew) * CC);
          mrow[r] = mnew;
        }
      }
      float psum[4];
#pragma unroll
      for (int r = 0; r < 4; ++r) psum[r] = 0.f;
#pragma unroll
      for (int si = 0; si < 4; ++si)
#pragma unroll
        for (int r = 0; r < 4; ++r) {
          float p = exp2f((sacc[si][r] - mrow[r]) * CC);
          psum[r] += p;
          Pl[w][(l4 * 4 + r) * 72 + si * 16 + l15] = f2bf(p);
        }
#pragma unroll
      for (int r = 0; r < 4; ++r) {
#pragma unroll
        for (int off = 1; off < 16; off <<= 1)
          psum[r] += __shfl_xor(psum[r], off);
        if (!defer) lrow[r] = lrow[r] * fac[r] + psum[r];
        else        lrow[r] += psum[r];
      }
      if (!defer) {
#pragma unroll
        for (int nt = 0; nt < 8; ++nt)
#pragma unroll
          for (int r = 0; r < 4; ++r) o[nt][r] *= fac[r];
      }

      __builtin_amdgcn_s_setprio(1);
#pragma unroll
      for (int kk = 0; kk < 2; ++kk) {
        short8 pf = *(const short8*)(&Pl[w][l15 * 72 + kk * 32 + l4 * 8]);
#pragma unroll
        for (int nt = 0; nt < 8; ++nt) {
          int h = nt * 16 + l15;
          int vb = (h * 128 + kk * 64 + l4 * 16) ^ SWZV(h);
          short8 vf = *(const short8*)((const char*)Vt + vb);
          o[nt] = __builtin_amdgcn_mfma_f32_16x16x32_bf16(pf, vf, o[nt], 0, 0, 0);
        }
      }
      __builtin_amdgcn_s_setprio(0);
    }
    __syncthreads();
    if (more) store_tile();
    __syncthreads();
  }

#pragma unroll
  for (int nt = 0; nt < 8; ++nt)
#pragma unroll
    for (int r = 0; r < 4; ++r) {
      size_t row = rowbase + q0 + w * 16 + l4 * 4 + r;
      int col = n * 128 + nt * 16 + l15;
      enc[row * (size_t)(nheads * 128) + col] = f2bf(o[nt][r] / lrow[r]);
    }
}

extern "C" void kernel_launch(void* const* d_in, const int* in_sizes, int n_in,
                              void* d_out, int out_size, void* d_ws, size_t ws_size,
                              hipStream_t stream) {
  const float* x     = (const float*)d_in[0];
  const float* w_q   = (const float*)d_in[1];
  const float* w_k   = (const float*)d_in[2];
  const float* w_v   = (const float*)d_in[3];
  const float* w_out = (const float*)d_in[4];
  const float* b_out = (const float*)d_in[5];
  const int* segpos  = (const int*)d_in[6];
  const int* wsz     = (const int*)d_in[8];
  float* out = (float*)d_out;

  const int BT = in_sizes[6];          // 4096
  const int W  = in_sizes[5];          // 2048
  const int H  = in_sizes[2] / W;      // 128
  const int NH = W / H;                // 16
  const int T  = 2048;
  const int NQKV = W + 2 * H;          // 2304

  char* ws = (char*)d_ws;
  short* xb    = (short*)ws;
  short* wqkvT = (short*)(ws + (size_t)BT * W * 2);
  short* woutT = (short*)(ws + (size_t)(BT * W + NQKV * W) * 2);
  short* qkv   = (short*)(ws + (size_t)(BT * W + NQKV * W + W * W) * 2);
  short* enc   = xb;

  int n8 = BT * W / 8;
  cast_x_bf16<<<(n8 + 255) / 256, 256, 0, stream>>>(x, xb, n8);

  dim3 tb(32, 8);
  transpose_cast<<<dim3(W / 32, W / 32), tb, 0, stream>>>(w_q, W, W, wqkvT, 0, W);
  transpose_cast<<<dim3(H / 32, W / 32), tb, 0, stream>>>(w_k, W, H, wqkvT, W, W);
  transpose_cast<<<dim3(H / 32, W / 32), tb, 0, stream>>>(w_v, W, H, wqkvT, W + H, W);
  transpose_cast<<<dim3(W / 32, W / 32), tb, 0, stream>>>(w_out, W, W, woutT, 0, W);

  gemm_bt<0><<<dim3(NQKV / 128, BT / 128), 256, 0, stream>>>(
      xb, wqkvT, BT, NQKV, W, NQKV, qkv, nullptr, nullptr);

  rope_kernel<<<BT, 256, 0, stream>>>(qkv, segpos, NH, H, NQKV);

  const int nqt = T / 128;
  const int bhc = (BT / T) * NH;
  attn_kernel<<<nqt * bhc, 512, 0, stream>>>(qkv, enc, wsz, T, NH, nqt, bhc);

  gemm_bt<1><<<dim3(W / 128, BT / 128), 256, 0, stream>>>(
      enc, woutT, BT, W, W, W, nullptr, out, b_out);
}

// Round 6
// 359.031 us; speedup vs baseline: 1.4503x; 1.0548x over previous
//
#include <hip/hip_runtime.h>
#include <hip/hip_bf16.h>
#include <stdint.h>

typedef __attribute__((ext_vector_type(8))) short short8;
typedef __attribute__((ext_vector_type(4))) float f32x4;

__device__ __forceinline__ float bf2f(short u) {
  return __uint_as_float(((unsigned)(unsigned short)u) << 16);
}
__device__ __forceinline__ short f2bf(float f) {
  unsigned x = __float_as_uint(f);
  unsigned r = (x + 0x7fffu + ((x >> 16) & 1u)) >> 16;
  return (short)r;
}

__device__ __forceinline__ void gload_lds16(const short* g, short* l) {
  __builtin_amdgcn_global_load_lds(
      (const __attribute__((address_space(1))) void*)g,
      (__attribute__((address_space(3))) void*)l, 16, 0, 0);
}

// ---------------- cast x (f32 -> bf16), 8 elems/thread ----------------
__global__ void cast_x_bf16(const float* __restrict__ in, short* __restrict__ out, int n8) {
  int i = blockIdx.x * blockDim.x + threadIdx.x;
  if (i >= n8) return;
  const float4* p = (const float4*)in + (size_t)i * 2;
  float4 a = p[0], b = p[1];
  short8 o;
  o[0] = f2bf(a.x); o[1] = f2bf(a.y); o[2] = f2bf(a.z); o[3] = f2bf(a.w);
  o[4] = f2bf(b.x); o[5] = f2bf(b.y); o[6] = f2bf(b.z); o[7] = f2bf(b.w);
  *((short8*)out + i) = o;
}

// ------------- transpose + cast: out[row_off + c][r] = in[r][c] -------------
__global__ void transpose_cast(const float* __restrict__ in, int R, int C,
                               short* __restrict__ out, int row_off, int ldo) {
  __shared__ float tile[32][33];
  int c0 = blockIdx.x * 32, r0 = blockIdx.y * 32;
  int tx = threadIdx.x, ty = threadIdx.y;
#pragma unroll
  for (int i = 0; i < 4; ++i)
    tile[ty + i * 8][tx] = in[(size_t)(r0 + ty + i * 8) * C + (c0 + tx)];
  __syncthreads();
#pragma unroll
  for (int i = 0; i < 4; ++i)
    out[(size_t)(row_off + c0 + ty + i * 8) * ldo + (r0 + tx)] =
        f2bf(tile[tx][ty + i * 8]);
}

// ---------- transpose V head (bf16): vT[b][h][t] = qkv[b][t][vcol+h] ----------
__global__ void transpose_v(const short* __restrict__ qkv, short* __restrict__ vT,
                            int T, int LD, int vcol) {
  __shared__ short tile[32][33];
  int t0 = blockIdx.x * 32, h0 = blockIdx.y * 32, b = blockIdx.z;
  int tx = threadIdx.x, ty = threadIdx.y;
#pragma unroll
  for (int i = 0; i < 4; ++i)
    tile[ty + i * 8][tx] = qkv[((size_t)b * T + t0 + ty + i * 8) * LD + vcol + h0 + tx];
  __syncthreads();
#pragma unroll
  for (int i = 0; i < 4; ++i)
    vT[((size_t)b * 128 + h0 + ty + i * 8) * T + t0 + tx] = tile[tx][ty + i * 8];
}

// ======== 256x256 8-phase GEMM: C = A[M,K] * Bt[N,K]^T (bf16 in) ========
// 8 waves (2M x 4N), BK=64, LDS 128KB double-buffered, T2 swizzle via
// pre-swizzled global_load_lds source, counted-vmcnt pipeline, T5 setprio.
template <int OUT_F32>
__global__ __launch_bounds__(512, 2)
void gemm256(const short* __restrict__ A, const short* __restrict__ Bt,
             int M, int N, int K, int ldc,
             short* __restrict__ outb, float* __restrict__ outf,
             const float* __restrict__ bias) {
  __shared__ short As[2][256 * 64];
  __shared__ short Bs[2][256 * 64];
  const int tid = threadIdx.x, lane = tid & 63, w = tid >> 6;
  const int wm = w >> 2, wn = w & 3;
  const int l15 = lane & 15, l4 = lane >> 4;
  const int m0 = blockIdx.y * 256, n0 = blockIdx.x * 256;
  const int sw = (l15 & 7) << 4;          // read-side XOR swizzle (row&7)<<4
  const int NT = K / 64;

  f32x4 acc[8][4] = {};
  short8 a[4][2], b[4][2];

  // stage one full 256x64 tile (A or B): 4 x gload_lds16 per thread.
  // source col pre-swizzled so linear LDS lands XOR-swizzled.
  auto stage = [&](short* dst, const short* src, int base0, int k0) {
#pragma unroll
    for (int i = 0; i < 4; ++i) {
      int chunk = i * 8 + w;                      // 32 chunks x 8 rows
      int r = chunk * 8 + (lane >> 3);
      int cs = ((lane & 7) ^ ((lane >> 3) & 7)) * 8;
      gload_lds16(src + (size_t)(base0 + r) * K + k0 + cs, dst + chunk * 512);
    }
  };

  auto rdA = [&](const short* buf, int mi, int kk) -> short8 {
    int row = wm * 128 + mi * 16 + l15;
    int byt = row * 128 + ((kk * 64 + l4 * 16) ^ sw);
    return *(const short8*)((const char*)buf + byt);
  };
  auto rdB = [&](const short* buf, int ni, int kk) -> short8 {
    int row = wn * 64 + ni * 16 + l15;
    int byt = row * 128 + ((kk * 64 + l4 * 16) ^ sw);
    return *(const short8*)((const char*)buf + byt);
  };

  // prologue: stage tile 0 into buffer 0, drain, barrier.
  stage(As[0], A, m0, 0);
  stage(Bs[0], Bt, n0, 0);
  asm volatile("s_waitcnt vmcnt(0)" ::: "memory");
  __builtin_amdgcn_s_barrier();

  for (int t = 0; t < NT; ++t) {
    const int bf = t & 1, nb = bf ^ 1;
    const bool pre = (t + 1 < NT);
    const short* Ab = As[bf];
    const short* Bb = Bs[bf];

    // ---- phase 0: read a[0..3], b[0..1]; stage A(t+1); mfma (m0-3 x n0-1)
#pragma unroll
    for (int mg = 0; mg < 4; ++mg) { a[mg][0] = rdA(Ab, mg, 0); a[mg][1] = rdA(Ab, mg, 1); }
#pragma unroll
    for (int ng = 0; ng < 2; ++ng) { b[ng][0] = rdB(Bb, ng, 0); b[ng][1] = rdB(Bb, ng, 1); }
    if (pre) stage(As[nb], A, m0, (t + 1) * 64);
    __builtin_amdgcn_s_barrier();
    __builtin_amdgcn_s_setprio(1);
#pragma unroll
    for (int mg = 0; mg < 4; ++mg)
#pragma unroll
      for (int ng = 0; ng < 2; ++ng) {
        acc[mg][ng] = __builtin_amdgcn_mfma_f32_16x16x32_bf16(a[mg][0], b[ng][0], acc[mg][ng], 0, 0, 0);
        acc[mg][ng] = __builtin_amdgcn_mfma_f32_16x16x32_bf16(a[mg][1], b[ng][1], acc[mg][ng], 0, 0, 0);
      }
    __builtin_amdgcn_s_setprio(0);
    __builtin_amdgcn_s_barrier();

    // ---- phase 1: read b[2..3]; stage B(t+1); mfma (m0-3 x n2-3)
#pragma unroll
    for (int ng = 2; ng < 4; ++ng) { b[ng][0] = rdB(Bb, ng, 0); b[ng][1] = rdB(Bb, ng, 1); }
    if (pre) stage(Bs[nb], Bt, n0, (t + 1) * 64);
    __builtin_amdgcn_s_barrier();
    __builtin_amdgcn_s_setprio(1);
#pragma unroll
    for (int mg = 0; mg < 4; ++mg)
#pragma unroll
      for (int ng = 2; ng < 4; ++ng) {
        acc[mg][ng] = __builtin_amdgcn_mfma_f32_16x16x32_bf16(a[mg][0], b[ng][0], acc[mg][ng], 0, 0, 0);
        acc[mg][ng] = __builtin_amdgcn_mfma_f32_16x16x32_bf16(a[mg][1], b[ng][1], acc[mg][ng], 0, 0, 0);
      }
    __builtin_amdgcn_s_setprio(0);
    __builtin_amdgcn_s_barrier();

    // ---- phase 2: read a[4..7]; mfma (m4-7 x n0-1)
#pragma unroll
    for (int mg = 0; mg < 4; ++mg) { a[mg][0] = rdA(Ab, mg + 4, 0); a[mg][1] = rdA(Ab, mg + 4, 1); }
    __builtin_amdgcn_s_barrier();
    __builtin_amdgcn_s_setprio(1);
#pragma unroll
    for (int mg = 0; mg < 4; ++mg)
#pragma unroll
      for (int ng = 0; ng < 2; ++ng) {
        acc[mg + 4][ng] = __builtin_amdgcn_mfma_f32_16x16x32_bf16(a[mg][0], b[ng][0], acc[mg + 4][ng], 0, 0, 0);
        acc[mg + 4][ng] = __builtin_amdgcn_mfma_f32_16x16x32_bf16(a[mg][1], b[ng][1], acc[mg + 4][ng], 0, 0, 0);
      }
    __builtin_amdgcn_s_setprio(0);
    __builtin_amdgcn_s_barrier();

    // ---- phase 3: mfma (m4-7 x n2-3); drain stage loads; barrier.
    __builtin_amdgcn_s_setprio(1);
#pragma unroll
    for (int mg = 0; mg < 4; ++mg)
#pragma unroll
      for (int ng = 2; ng < 4; ++ng) {
        acc[mg + 4][ng] = __builtin_amdgcn_mfma_f32_16x16x32_bf16(a[mg][0], b[ng][0], acc[mg + 4][ng], 0, 0, 0);
        acc[mg + 4][ng] = __builtin_amdgcn_mfma_f32_16x16x32_bf16(a[mg][1], b[ng][1], acc[mg + 4][ng], 0, 0, 0);
      }
    __builtin_amdgcn_s_setprio(0);
    asm volatile("s_waitcnt vmcnt(0)" ::: "memory");
    __builtin_amdgcn_s_barrier();
  }

  // epilogue
#pragma unroll
  for (int mi = 0; mi < 8; ++mi)
#pragma unroll
    for (int ni = 0; ni < 4; ++ni)
#pragma unroll
      for (int r = 0; r < 4; ++r) {
        int row = m0 + wm * 128 + mi * 16 + l4 * 4 + r;
        int col = n0 + wn * 64 + ni * 16 + l15;
        if (OUT_F32)
          outf[(size_t)row * ldc + col] = acc[mi][ni][r] + bias[col];
        else
          outb[(size_t)row * ldc + col] = f2bf(acc[mi][ni][r]);
      }
}

// ---------------- RoPE in-place on qkv ----------------
__global__ void rope_kernel(short* __restrict__ qkv, const int* __restrict__ segpos,
                            int nheads, int hd, int ld) {
  const int row = blockIdx.x;
  const float pos = (float)segpos[row];
  short* base = qkv + (size_t)row * ld;
  const int quarter = hd >> 2;
  const int npairs_q = nheads * quarter;
  const int total = npairs_q + quarter;
  for (int p = threadIdx.x; p < total; p += blockDim.x) {
    int i, off;
    if (p < npairs_q) { off = (p >> 5) * hd; i = p & 31; }
    else              { off = nheads * hd;  i = p - npairs_q; }
    float ang = pos * exp2f(-(float)i * (13.287712379549449f / (float)quarter));
    float s, c;
    sincosf(ang, &s, &c);
    float a = bf2f(base[off + i]);
    float b = bf2f(base[off + quarter + i]);
    base[off + i]           = f2bf(a * c - b * s);
    base[off + quarter + i] = f2bf(b * c + a * s);
  }
}

// ---------------- windowed causal flash attention (MQA), H=128 ----------------
// 512 threads = 8 waves x 16 q-rows = 128 q-rows/block. V pre-transposed (vT).
__global__ __launch_bounds__(512)
void attn_kernel(const short* __restrict__ qkv, const short* __restrict__ vT,
                 short* __restrict__ enc,
                 const int* __restrict__ wsz_p, int T, int nheads, int nqt, int bhc) {
  const int window = wsz_p[0];
  const int i = blockIdx.x;
  const int qt = nqt - 1 - (i / bhc);   // LPT: heavy tiles first
  const int bh = i % bhc;
  const int b = bh / nheads, n = bh % nheads;
  const int tid = threadIdx.x, lane = tid & 63, w = tid >> 6;
  const int l15 = lane & 15, l4 = lane >> 4;
  const int q0 = qt * 128;
  const size_t rowbase = (size_t)b * T;
  const int LD = nheads * 128 + 256;    // 2304
  const int kcol = nheads * 128;
  const float CC = 0.08838834764831845f * 1.4426950408889634f;

  __shared__ short Ks[64 * 128];        // [s][h], byte ^ ((s&7)<<4)
  __shared__ short Vt[128 * 64];        // [h][s], byte ^ ((h&7)<<4)
  __shared__ short Pl[8][16 * 72];

  short8 qf[4];
  {
    const short* qptr = qkv + (rowbase + q0 + w * 16 + l15) * LD + n * 128 + l4 * 8;
#pragma unroll
    for (int kk = 0; kk < 4; ++kk) qf[kk] = *(const short8*)(qptr + kk * 32);
  }
  f32x4 o[8] = {};
  float mrow[4], lrow[4];
#pragma unroll
  for (int r = 0; r < 4; ++r) { mrow[r] = -1e30f; lrow[r] = 0.f; }

  const int tmin = q0 + w * 16, tmax = tmin + 15;
  int st_lo = q0 - window; if (st_lo < 0) st_lo = 0; st_lo >>= 6;
  const int st_hi = (q0 + 127) >> 6;

  short8 kreg[2], vreg[2];
  auto load_tile = [&](int s0) {
#pragma unroll
    for (int it = 0; it < 2; ++it) {
      int c = it * 512 + tid;
      kreg[it] = *(const short8*)(qkv + (rowbase + s0 + (c >> 4)) * (size_t)LD + kcol + (c & 15) * 8);
      vreg[it] = *(const short8*)(vT + ((size_t)b * 128 + (c >> 3)) * T + s0 + (c & 7) * 8);
    }
  };
  auto store_tile = [&]() {
#pragma unroll
    for (int it = 0; it < 2; ++it) {
      int c = it * 512 + tid;
      int r = c >> 4;
      *(short8*)((char*)Ks + ((r * 256 + (c & 15) * 16) ^ ((r & 7) << 4))) = kreg[it];
      int h = c >> 3;
      *(short8*)((char*)Vt + ((h * 128 + (c & 7) * 16) ^ ((h & 7) << 4))) = vreg[it];
    }
  };

  load_tile(st_lo * 64);
  store_tile();
  __syncthreads();

  for (int st = st_lo; st <= st_hi; ++st) {
    const int s0 = st * 64;
    const bool more = (st < st_hi);
    if (more) load_tile(s0 + 64);

    const bool active = (s0 <= tmax) && (tmin <= s0 + 63 + window);
    if (active) {
      f32x4 sacc[4];
      __builtin_amdgcn_s_setprio(1);
#pragma unroll
      for (int si = 0; si < 4; ++si) {
        f32x4 acc = {};
        int srow = si * 16 + l15;
#pragma unroll
        for (int kk = 0; kk < 4; ++kk) {
          int byt = (srow * 256 + (kk * 32 + l4 * 8) * 2) ^ ((srow & 7) << 4);
          short8 kf = *(const short8*)((const char*)Ks + byt);
          acc = __builtin_amdgcn_mfma_f32_16x16x32_bf16(qf[kk], kf, acc, 0, 0, 0);
        }
        sacc[si] = acc;
      }
      __builtin_amdgcn_s_setprio(0);

      const int trow0 = q0 + w * 16 + l4 * 4;
      const bool full = (s0 + 63 <= tmin) && (tmax <= s0 + window);
      float mt[4];
      if (full) {
#pragma unroll
        for (int r = 0; r < 4; ++r)
          mt[r] = fmaxf(fmaxf(sacc[0][r], sacc[1][r]), fmaxf(sacc[2][r], sacc[3][r]));
      } else {
#pragma unroll
        for (int r = 0; r < 4; ++r) mt[r] = -1e30f;
#pragma unroll
        for (int si = 0; si < 4; ++si) {
          int s = s0 + si * 16 + l15;
#pragma unroll
          for (int r = 0; r < 4; ++r) {
            int t = trow0 + r;
            float v = (s <= t && t <= s + window) ? sacc[si][r] : -1e30f;
            sacc[si][r] = v;
            mt[r] = fmaxf(mt[r], v);
          }
        }
      }
#pragma unroll
      for (int r = 0; r < 4; ++r)
#pragma unroll
        for (int off = 1; off < 16; off <<= 1)
          mt[r] = fmaxf(mt[r], __shfl_xor(mt[r], off));

      bool dfr = true;
#pragma unroll
      for (int r = 0; r < 4; ++r) dfr = dfr && ((mt[r] - mrow[r]) * CC <= 8.0f);
      const bool defer = __all(dfr);
      float fac[4];
      if (!defer) {
#pragma unroll
        for (int r = 0; r < 4; ++r) {
          float mnew = fmaxf(mrow[r], mt[r]);
          fac[r] = exp2f((mrow[r] - mnew) * CC);
          mrow[r] = mnew;
        }
      }
      float psum[4];
#pragma unroll
      for (int r = 0; r < 4; ++r) psum[r] = 0.f;
#pragma unroll
      for (int si = 0; si < 4; ++si)
#pragma unroll
        for (int r = 0; r < 4; ++r) {
          float p = exp2f((sacc[si][r] - mrow[r]) * CC);
          psum[r] += p;
          Pl[w][(l4 * 4 + r) * 72 + si * 16 + l15] = f2bf(p);
        }
#pragma unroll
      for (int r = 0; r < 4; ++r) {
#pragma unroll
        for (int off = 1; off < 16; off <<= 1)
          psum[r] += __shfl_xor(psum[r], off);
        if (!defer) lrow[r] = lrow[r] * fac[r] + psum[r];
        else        lrow[r] += psum[r];
      }
      if (!defer) {
#pragma unroll
        for (int nt = 0; nt < 8; ++nt)
#pragma unroll
          for (int r = 0; r < 4; ++r) o[nt][r] *= fac[r];
      }

      __builtin_amdgcn_s_setprio(1);
#pragma unroll
      for (int kk = 0; kk < 2; ++kk) {
        short8 pf = *(const short8*)(&Pl[w][l15 * 72 + kk * 32 + l4 * 8]);
#pragma unroll
        for (int nt = 0; nt < 8; ++nt) {
          int h = nt * 16 + l15;
          int vb = (h * 128 + kk * 64 + l4 * 16) ^ ((h & 7) << 4);
          short8 vf = *(const short8*)((const char*)Vt + vb);
          o[nt] = __builtin_amdgcn_mfma_f32_16x16x32_bf16(pf, vf, o[nt], 0, 0, 0);
        }
      }
      __builtin_amdgcn_s_setprio(0);
    }
    __syncthreads();
    if (more) store_tile();
    __syncthreads();
  }

#pragma unroll
  for (int nt = 0; nt < 8; ++nt)
#pragma unroll
    for (int r = 0; r < 4; ++r) {
      size_t row = rowbase + q0 + w * 16 + l4 * 4 + r;
      int col = n * 128 + nt * 16 + l15;
      enc[row * (size_t)(nheads * 128) + col] = f2bf(o[nt][r] / lrow[r]);
    }
}

extern "C" void kernel_launch(void* const* d_in, const int* in_sizes, int n_in,
                              void* d_out, int out_size, void* d_ws, size_t ws_size,
                              hipStream_t stream) {
  const float* x     = (const float*)d_in[0];
  const float* w_q   = (const float*)d_in[1];
  const float* w_k   = (const float*)d_in[2];
  const float* w_v   = (const float*)d_in[3];
  const float* w_out = (const float*)d_in[4];
  const float* b_out = (const float*)d_in[5];
  const int* segpos  = (const int*)d_in[6];
  const int* wsz     = (const int*)d_in[8];
  float* out = (float*)d_out;

  const int BT = in_sizes[6];          // 4096
  const int W  = in_sizes[5];          // 2048
  const int H  = in_sizes[2] / W;      // 128
  const int NH = W / H;                // 16
  const int T  = 2048;
  const int B  = BT / T;               // 2
  const int NQKV = W + 2 * H;          // 2304

  char* ws = (char*)d_ws;
  short* xb    = (short*)ws;                                            // BT*W
  short* wqkvT = (short*)(ws + (size_t)BT * W * 2);                     // NQKV*W
  short* woutT = (short*)(ws + (size_t)(BT * W + NQKV * W) * 2);        // W*W
  short* qkv   = (short*)(ws + (size_t)(BT * W + NQKV * W + W * W) * 2);// BT*NQKV
  // vTp (B*H*T = 1MB) aliases the wqkvT region, which is dead after GEMM1.
  // Keeps ws high-water mark identical to the R4 run that passed.
  short* vTp   = wqkvT;
  short* enc   = xb;

  int n8 = BT * W / 8;
  cast_x_bf16<<<(n8 + 255) / 256, 256, 0, stream>>>(x, xb, n8);

  dim3 tb(32, 8);
  transpose_cast<<<dim3(W / 32, W / 32), tb, 0, stream>>>(w_q, W, W, wqkvT, 0, W);
  transpose_cast<<<dim3(H / 32, W / 32), tb, 0, stream>>>(w_k, W, H, wqkvT, W, W);
  transpose_cast<<<dim3(H / 32, W / 32), tb, 0, stream>>>(w_v, W, H, wqkvT, W + H, W);
  transpose_cast<<<dim3(W / 32, W / 32), tb, 0, stream>>>(w_out, W, W, woutT, 0, W);

  gemm256<0><<<dim3(NQKV / 256, BT / 256), 512, 0, stream>>>(
      xb, wqkvT, BT, NQKV, W, NQKV, qkv, nullptr, nullptr);

  rope_kernel<<<BT, 256, 0, stream>>>(qkv, segpos, NH, H, NQKV);

  transpose_v<<<dim3(T / 32, H / 32, B), tb, 0, stream>>>(qkv, vTp, T, NQKV, NH * H + H);

  const int nqt = T / 128;
  const int bhc = B * NH;
  attn_kernel<<<nqt * bhc, 512, 0, stream>>>(qkv, vTp, enc, wsz, T, NH, nqt, bhc);

  gemm256<1><<<dim3(W / 256, BT / 256), 512, 0, stream>>>(
      enc, woutT, BT, W, W, W, nullptr, out, b_out);
}